// Round 1
// baseline (1813.116 us; speedup 1.0000x reference)
//
#include <hip/hip_runtime.h>
#include <math.h>

constexpr int IN_DIM = 64;
constexpr int NG     = 20;
constexpr int KDIM   = IN_DIM + NG;   // 84
constexpr int OUTD   = 128;
constexpr int TILE_E = 32;            // edges per block-iteration
constexpr int FS     = 88;            // featS row stride (floats), rows 16B-aligned
constexpr int BLOCK  = 256;

__device__ __forceinline__ void fma4(float4& a, float s, const float4& w) {
    a.x = fmaf(s, w.x, a.x);
    a.y = fmaf(s, w.y, a.y);
    a.z = fmaf(s, w.z, a.z);
    a.w = fmaf(s, w.w, a.w);
}

__global__ __launch_bounds__(BLOCK, 2)
void bond_embed_kernel(const float* __restrict__ bond_feat,
                       const int*   __restrict__ bond_index,
                       const float* __restrict__ pos,
                       const float* __restrict__ Wg,
                       const float* __restrict__ bg,
                       float*       __restrict__ out,
                       int E, int n_tiles)
{
    __shared__ float Ws[KDIM * OUTD];     // 43008 B
    __shared__ float featS[TILE_E * FS];  // 11264 B

    const int t = threadIdx.x;

    // Stage W into LDS once per block (persistent blocks).
    for (int i = t; i < KDIM * OUTD; i += BLOCK) Ws[i] = Wg[i];

    const int o4 = (t & 31) * 4;          // this thread's 4 consecutive outputs
    const int em = (t >> 5) * 4;          // this thread's 4 edges within the tile
    const float4 bias = *(const float4*)(bg + o4);

    for (int tile = blockIdx.x; tile < n_tiles; tile += gridDim.x) {
        const long long e0 = (long long)tile * TILE_E;

        __syncthreads();  // featS readers from previous iter done

        // ---- stage bond_feat: 32 edges x 64 floats = 512 float4, 2 per thread ----
        {
            int i = t;                       // edges 0..15
            int e = i >> 4, v = i & 15;
            long long eg = e0 + e;
            float4 f = make_float4(0.f, 0.f, 0.f, 0.f);
            if (eg < E) f = ((const float4*)(bond_feat + eg * (long long)IN_DIM))[v];
            *((float4*)(featS + e * FS + v * 4)) = f;

            i = t + BLOCK;                   // edges 16..31
            e = i >> 4; v = i & 15;
            eg = e0 + e;
            f = make_float4(0.f, 0.f, 0.f, 0.f);
            if (eg < E) f = ((const float4*)(bond_feat + eg * (long long)IN_DIM))[v];
            *((float4*)(featS + e * FS + v * 4)) = f;
        }

        // ---- distance + gaussian smearing: one thread per edge (t < 32) ----
        if (t < TILE_E) {
            long long eg = e0 + t;
            if (eg < E) {
                int i0 = bond_index[eg];
                int i1 = bond_index[(long long)E + eg];
                float dx = pos[i0 * 3 + 0] - pos[i1 * 3 + 0];
                float dy = pos[i0 * 3 + 1] - pos[i1 * 3 + 1];
                float dz = pos[i0 * 3 + 2] - pos[i1 * 3 + 2];
                float dist = sqrtf(dx * dx + dy * dy + dz * dz);
                const float step  = 10.0f / 19.0f;
                const float coeff = -0.5f / (step * step);
                #pragma unroll
                for (int g = 0; g < NG; ++g) {
                    float d = dist - (float)g * step;
                    featS[t * FS + IN_DIM + g] = __expf(coeff * d * d);
                }
            }
        }

        __syncthreads();

        // ---- compute: 4 edges x 4 outputs per thread, k-step 4 ----
        float4 acc0 = bias, acc1 = bias, acc2 = bias, acc3 = bias;

        #pragma unroll 3
        for (int k = 0; k < KDIM; k += 4) {
            float4 w0 = *(const float4*)(Ws + (k + 0) * OUTD + o4);
            float4 w1 = *(const float4*)(Ws + (k + 1) * OUTD + o4);
            float4 w2 = *(const float4*)(Ws + (k + 2) * OUTD + o4);
            float4 w3 = *(const float4*)(Ws + (k + 3) * OUTD + o4);

            float4 f0 = *(const float4*)(featS + (em + 0) * FS + k);
            float4 f1 = *(const float4*)(featS + (em + 1) * FS + k);
            float4 f2 = *(const float4*)(featS + (em + 2) * FS + k);
            float4 f3 = *(const float4*)(featS + (em + 3) * FS + k);

            fma4(acc0, f0.x, w0); fma4(acc0, f0.y, w1); fma4(acc0, f0.z, w2); fma4(acc0, f0.w, w3);
            fma4(acc1, f1.x, w0); fma4(acc1, f1.y, w1); fma4(acc1, f1.z, w2); fma4(acc1, f1.w, w3);
            fma4(acc2, f2.x, w0); fma4(acc2, f2.y, w1); fma4(acc2, f2.z, w2); fma4(acc2, f2.w, w3);
            fma4(acc3, f3.x, w0); fma4(acc3, f3.y, w1); fma4(acc3, f3.z, w2); fma4(acc3, f3.w, w3);
        }

        // ---- write out ----
        long long eg = e0 + em;
        if (eg + 0 < E) *((float4*)(out + (eg + 0) * (long long)OUTD + o4)) = acc0;
        if (eg + 1 < E) *((float4*)(out + (eg + 1) * (long long)OUTD + o4)) = acc1;
        if (eg + 2 < E) *((float4*)(out + (eg + 2) * (long long)OUTD + o4)) = acc2;
        if (eg + 3 < E) *((float4*)(out + (eg + 3) * (long long)OUTD + o4)) = acc3;
    }
}

extern "C" void kernel_launch(void* const* d_in, const int* in_sizes, int n_in,
                              void* d_out, int out_size, void* d_ws, size_t ws_size,
                              hipStream_t stream) {
    const float* bond_feat  = (const float*)d_in[0];
    const int*   bond_index = (const int*)d_in[1];
    const float* pos        = (const float*)d_in[2];
    const float* W          = (const float*)d_in[3];
    const float* b          = (const float*)d_in[4];
    float* out = (float*)d_out;

    int E = in_sizes[0] / IN_DIM;
    int n_tiles = (E + TILE_E - 1) / TILE_E;
    int grid = 512;                    // 2 blocks/CU x 256 CUs, persistent
    if (grid > n_tiles) grid = n_tiles;

    hipLaunchKernelGGL(bond_embed_kernel, dim3(grid), dim3(BLOCK), 0, stream,
                       bond_feat, bond_index, pos, W, b, out, E, n_tiles);
}